// Round 16
// baseline (326.692 us; speedup 1.0000x reference)
//
#include <hip/hip_runtime.h>

#define NN 20000
#define NE 640000
#define Cc 128
#define C2 256
#define BN_EPS 1e-5f

typedef __attribute__((ext_vector_type(8))) short bf16x8;
typedef __attribute__((ext_vector_type(4))) float f32x4;

// ---- workspace layout (float offsets) ----
#define WS_P     0                      // [NN*Cc]
#define WS_Q     (NN*Cc)                // [NN*Cc]
#define WS_CNTT  (2*NN*Cc)              // [NN] float
#define WS_CNTS  (2*NN*Cc + NN)         // [NN] int
#define WS_STATS (2*NN*Cc + 2*NN)       // [768]: sum1[256], sq1[256], sum2[128], sq2[128]
#define WS_W1PT  (WS_STATS + 768)       // [256*128] transposed folded W1: [c][o]
#define WS_B1P   (WS_W1PT + C2*Cc)      // [128]
#define WS_W2BF  (WS_B1P + Cc)          // ushort[128*128] folded W2 bf16: [o][c]
#define WS_B2P   (WS_W2BF + Cc*Cc)      // [128]

// z (bf16) for edge e lives in the FIRST 256 B of out-row e's 512 B slot:
// ushort index e*256 + c. Written by k_stats2, read (then overwritten) by
// k_out_mfma's own wave -> no race (reads complete into regs before stores).

// fp32 -> bf16 round-to-nearest-even
static __device__ inline unsigned short f2bf(float f) {
  union { float f; unsigned u; } v; v.f = f;
  unsigned r = v.u + 0x7fffu + ((v.u >> 16) & 1u);
  return (unsigned short)(r >> 16);
}

__global__ void k_zero(float* __restrict__ stats, int* __restrict__ cntS) {
  int i = blockIdx.x * blockDim.x + threadIdx.x;
  if (i < 768) stats[i] = 0.0f;
  if (i < NN) cntS[i] = 0;
}

__global__ void k_cnt(const int* __restrict__ src, int* __restrict__ cntS) {
  int e = blockIdx.x * blockDim.x + threadIdx.x;
  if (e < NE) atomicAdd(&cntS[src[e]], 1);
}

// one block (128 threads) per node: segment sum of x[src] over the node's
// contiguous (tgt sorted) edge range; 8 loads in flight per iteration.
__global__ void k_nbr(const float* __restrict__ x, const int* __restrict__ tgt,
                      const int* __restrict__ src, float* __restrict__ nbr,
                      float* __restrict__ cntT) {
  int node = blockIdx.x;
  int a = 0, b = NE;
  while (a < b) { int m = (a + b) >> 1; if (tgt[m] < node) a = m + 1; else b = m; }
  int lo = a;
  b = NE;
  while (a < b) { int m = (a + b) >> 1; if (tgt[m] <= node) a = m + 1; else b = m; }
  int hi = a;
  int c = threadIdx.x;
  float a0 = 0.f, a1 = 0.f, a2 = 0.f, a3 = 0.f;
  int e = lo;
  for (; e + 7 < hi; e += 8) {
    int s0 = src[e],     s1 = src[e + 1], s2 = src[e + 2], s3 = src[e + 3];
    int s4 = src[e + 4], s5 = src[e + 5], s6 = src[e + 6], s7 = src[e + 7];
    float v0 = x[(size_t)s0 * Cc + c], v1 = x[(size_t)s1 * Cc + c];
    float v2 = x[(size_t)s2 * Cc + c], v3 = x[(size_t)s3 * Cc + c];
    float v4 = x[(size_t)s4 * Cc + c], v5 = x[(size_t)s5 * Cc + c];
    float v6 = x[(size_t)s6 * Cc + c], v7 = x[(size_t)s7 * Cc + c];
    a0 += v0 + v4; a1 += v1 + v5; a2 += v2 + v6; a3 += v3 + v7;
  }
  for (; e + 3 < hi; e += 4) {
    int s0 = src[e], s1 = src[e + 1], s2 = src[e + 2], s3 = src[e + 3];
    a0 += x[(size_t)s0 * Cc + c];
    a1 += x[(size_t)s1 * Cc + c];
    a2 += x[(size_t)s2 * Cc + c];
    a3 += x[(size_t)s3 * Cc + c];
  }
  for (; e < hi; ++e) a0 += x[(size_t)src[e] * Cc + c];
  nbr[node * Cc + c] = (a0 + a1) + (a2 + a3);
  if (c == 0) cntT[node] = (float)(hi - lo);
}

// BN1 stats: count-weighted sums over nodes. 512 blocks x 512 threads
// (4 node-stripes x 128 channels, LDS-combine) -> 16 waves/CU vs old 2.
__global__ __launch_bounds__(512) void k_stats1(const float* __restrict__ nbr,
                                                const float* __restrict__ x,
                                                const float* __restrict__ cntT,
                                                const int* __restrict__ cntS,
                                                float* __restrict__ stats) {
  __shared__ float ls[3][4][Cc];
  int c = threadIdx.x & 127;
  int y = threadIdx.x >> 7;       // 0..3
  float sa = 0.f, qa = 0.f, sb = 0.f, qb = 0.f;
  for (int t = blockIdx.x + y * 512; t < NN; t += 2048) {
    float ct = cntT[t];
    float cs = (float)cntS[t];
    float v1 = nbr[t * Cc + c];
    float v2 = x[t * Cc + c];
    sa += ct * v1; qa += ct * v1 * v1;
    sb += cs * v2; qb += cs * v2 * v2;
  }
  if (y) {
    ls[y - 1][0][c] = sa; ls[y - 1][1][c] = qa;
    ls[y - 1][2][c] = sb; ls[y - 1][3][c] = qb;
  }
  __syncthreads();
  if (!y) {
    #pragma unroll
    for (int j = 0; j < 3; ++j) {
      sa += ls[j][0][c]; qa += ls[j][1][c];
      sb += ls[j][2][c]; qb += ls[j][3][c];
    }
    atomicAdd(&stats[c], sa);
    atomicAdd(&stats[256 + c], qa);
    atomicAdd(&stats[128 + c], sb);
    atomicAdd(&stats[256 + 128 + c], qb);
  }
}

// fold BN1 into W1: W1pT[c][o] = W1[o][c]*a1[c];  b1p[o] = b1[o] + sum_c W1[o][c]*c1[c]
__global__ void k_fold1(const float* __restrict__ W1, const float* __restrict__ b1,
                        const float* __restrict__ g1, const float* __restrict__ be1,
                        const float* __restrict__ stats,
                        float* __restrict__ W1pT, float* __restrict__ b1p) {
  __shared__ float red[C2];
  int o = blockIdx.x, c = threadIdx.x;
  const float inv = 1.0f / (float)NE;
  float mu = stats[c] * inv;
  float var = stats[256 + c] * inv - mu * mu;
  float a = g1[c] * rsqrtf(var + BN_EPS);
  float cc = be1[c] - mu * a;
  float w = W1[o * C2 + c];
  W1pT[c * Cc + o] = w * a;
  red[c] = w * cc;
  __syncthreads();
  for (int s = 128; s > 0; s >>= 1) { if (c < s) red[c] += red[c + s]; __syncthreads(); }
  if (c == 0) b1p[o] = b1[o] + red[0];
}

// P = nbr_sum @ W1a'.T ; Q = x @ W1b'.T   (blockIdx.y selects half)
__global__ __launch_bounds__(256) void k_pq(const float* __restrict__ nbr,
                                            const float* __restrict__ x,
                                            const float* __restrict__ W1pT,
                                            float* __restrict__ P,
                                            float* __restrict__ Q) {
  __shared__ float Ar[32][128];
  const int half = blockIdx.y;
  const float* __restrict__ A = half ? x : nbr;
  float* __restrict__ Out = half ? Q : P;
  const float* __restrict__ Wt = W1pT + (half ? Cc * Cc : 0);  // [128 c][128 o]
  int tid = threadIdx.x;
  int r0 = blockIdx.x * 32;
  for (int i = tid; i < 32 * 128; i += 256) {
    int r = i >> 7, c = i & 127;
    Ar[r][c] = A[(r0 + r) * Cc + c];
  }
  __syncthreads();
  int tx = tid & 31, ty = tid >> 5;
  float acc[4][4] = {};
  #pragma unroll 4
  for (int c = 0; c < 128; ++c) {
    float4 w = *(const float4*)&Wt[c * Cc + tx * 4];
    float a0 = Ar[ty * 4 + 0][c], a1 = Ar[ty * 4 + 1][c];
    float a2 = Ar[ty * 4 + 2][c], a3 = Ar[ty * 4 + 3][c];
    acc[0][0] += a0 * w.x; acc[0][1] += a0 * w.y; acc[0][2] += a0 * w.z; acc[0][3] += a0 * w.w;
    acc[1][0] += a1 * w.x; acc[1][1] += a1 * w.y; acc[1][2] += a1 * w.z; acc[1][3] += a1 * w.w;
    acc[2][0] += a2 * w.x; acc[2][1] += a2 * w.y; acc[2][2] += a2 * w.z; acc[2][3] += a2 * w.w;
    acc[3][0] += a3 * w.x; acc[3][1] += a3 * w.y; acc[3][2] += a3 * w.z; acc[3][3] += a3 * w.w;
  }
  #pragma unroll
  for (int i = 0; i < 4; ++i) {
    int node = r0 + ty * 4 + i;
    float4 v = make_float4(acc[i][0], acc[i][1], acc[i][2], acc[i][3]);
    *(float4*)&Out[node * Cc + tx * 4] = v;
  }
}

// BN2 stats + z materialization. 1250 blocks x 512 threads as 8 octet-stripes
// x 64 channel-PAIRS: float2 gathers (8B/lane), ushort2 z-stores (4B/lane).
// Same 512-edge sorted-tgt window, 8-deep ILP, 1 atomic set per block.
__global__ __launch_bounds__(512) void k_stats2(const float* __restrict__ P,
                                                const float* __restrict__ Q,
                                                const float* __restrict__ b1p,
                                                const int* __restrict__ tgt,
                                                const int* __restrict__ src,
                                                float* __restrict__ stats,
                                                unsigned short* __restrict__ zout) {
  __shared__ float s2[7][Cc], q2[7][Cc];
  int cp = threadIdx.x & 63;      // channel pair 0..63
  int y = threadIdx.x >> 6;       // stripe 0..7
  int c0 = cp * 2;
  int e0 = blockIdx.x * 512;
  float2 b = *(const float2*)&b1p[c0];
  float s0 = 0.f, s1 = 0.f, q0 = 0.f, q1 = 0.f;
  for (int e = e0 + y * 8; e < e0 + 512; e += 64) {
    int t[8], sr[8];
    #pragma unroll
    for (int j = 0; j < 8; ++j) { t[j] = tgt[e + j]; sr[j] = src[e + j]; }
    float2 pv[8], qv[8];
    #pragma unroll
    for (int j = 0; j < 8; ++j) pv[j] = *(const float2*)&P[(size_t)t[j] * Cc + c0];
    #pragma unroll
    for (int j = 0; j < 8; ++j) qv[j] = *(const float2*)&Q[(size_t)sr[j] * Cc + c0];
    #pragma unroll
    for (int j = 0; j < 8; ++j) {
      float z0 = fmaxf(pv[j].x + qv[j].x + b.x, 0.f);
      float z1 = fmaxf(pv[j].y + qv[j].y + b.y, 0.f);
      ushort2 zz; zz.x = f2bf(z0); zz.y = f2bf(z1);
      *(ushort2*)&zout[(size_t)(e + j) * 256 + c0] = zz;
      s0 += z0; s1 += z1; q0 += z0 * z0; q1 += z1 * z1;
    }
  }
  if (y) { s2[y - 1][c0] = s0; s2[y - 1][c0 + 1] = s1;
           q2[y - 1][c0] = q0; q2[y - 1][c0 + 1] = q1; }
  __syncthreads();
  if (!y) {
    #pragma unroll
    for (int j = 0; j < 7; ++j) {
      s0 += s2[j][c0]; s1 += s2[j][c0 + 1];
      q0 += q2[j][c0]; q1 += q2[j][c0 + 1];
    }
    atomicAdd(&stats[512 + c0], s0);
    atomicAdd(&stats[512 + c0 + 1], s1);
    atomicAdd(&stats[640 + c0], q0);
    atomicAdd(&stats[640 + c0 + 1], q1);
  }
}

// fold BN2 into W2, emit bf16 [o][c] weights + fp32 bias
__global__ void k_fold2(const float* __restrict__ W2, const float* __restrict__ b2,
                        const float* __restrict__ g2, const float* __restrict__ be2,
                        const float* __restrict__ stats,
                        unsigned short* __restrict__ W2bf, float* __restrict__ b2p) {
  __shared__ float red[Cc];
  int o = blockIdx.x, c = threadIdx.x;
  const float inv = 1.0f / (float)NE;
  float mu = stats[512 + c] * inv;
  float var = stats[640 + c] * inv - mu * mu;
  float a = g2[c] * rsqrtf(var + BN_EPS);
  float cc = be2[c] - mu * a;
  float w = W2[o * Cc + c];
  W2bf[o * Cc + c] = f2bf(w * a);
  red[c] = w * cc;
  __syncthreads();
  for (int s = 64; s > 0; s >>= 1) { if (c < s) red[c] += red[c + s]; __syncthreads(); }
  if (c == 0) b2p[o] = b2[o] + red[0];
}

// out[e][o] = relu( z[e]@W2' + b2' ): pure streaming bf16 MFMA GEMM.
// Operand-SWAPPED (A=W rows=outs, B=z cols=edges): 8 float4 stores per lane.
// z read from out-row slot into regs before stores (safe in-place overwrite).
#define WPAD 136
__global__ __launch_bounds__(256) void k_out_mfma(const unsigned short* __restrict__ zin,
                                                  const unsigned short* __restrict__ W2bf,
                                                  const float* __restrict__ b2p,
                                                  float* __restrict__ out) {
  __shared__ unsigned short Wl[128 * WPAD];  // 34816 B -> 4 blocks/CU
  int tid = threadIdx.x;
  int e0 = blockIdx.x * 64;

  // stage folded-bf16 W2 [o][c] -> LDS (coalesced 16B loads)
  for (int i = tid; i < 2048; i += 256) {
    int row = i >> 4, col = (i & 15) * 8;
    *(bf16x8*)&Wl[row * WPAD + col] = *(const bf16x8*)&W2bf[row * Cc + col];
  }

  int w = tid >> 6, l = tid & 63;
  int la = l & 15, kb = l >> 4;
  int e = e0 + w * 16 + la;

  // load all 4 B-fragments (full z row slice) into registers up front
  bf16x8 zfr[4];
  #pragma unroll
  for (int kk = 0; kk < 4; ++kk)
    zfr[kk] = *(const bf16x8*)&zin[(size_t)e * 256 + kk * 32 + kb * 8];
  __syncthreads();

  f32x4 acc[8];
  #pragma unroll
  for (int n = 0; n < 8; ++n) acc[n] = (f32x4){0.f, 0.f, 0.f, 0.f};

  #pragma unroll
  for (int kk = 0; kk < 4; ++kk) {        // K = 128 in 4 steps of 32
    #pragma unroll
    for (int n = 0; n < 8; ++n) {         // 8 out-tiles of 16
      bf16x8 wa = *(const bf16x8*)&Wl[(n * 16 + la) * WPAD + kk * 32 + kb * 8];
      acc[n] = __builtin_amdgcn_mfma_f32_16x16x32_bf16(wa, zfr[kk], acc[n], 0, 0, 0);
    }
  }

  // D layout: col(edge) = la, row(out) = kb*4 + r -> contiguous float4 per lane
  #pragma unroll
  for (int n = 0; n < 8; ++n) {
    int o0 = n * 16 + kb * 4;
    float4 bb = *(const float4*)&b2p[o0];
    float4 v;
    v.x = fmaxf(acc[n][0] + bb.x, 0.f);
    v.y = fmaxf(acc[n][1] + bb.y, 0.f);
    v.z = fmaxf(acc[n][2] + bb.z, 0.f);
    v.w = fmaxf(acc[n][3] + bb.w, 0.f);
    *(float4*)&out[(size_t)e * Cc + o0] = v;
  }
}

extern "C" void kernel_launch(void* const* d_in, const int* in_sizes, int n_in,
                              void* d_out, int out_size, void* d_ws, size_t ws_size,
                              hipStream_t stream) {
  (void)in_sizes; (void)n_in; (void)out_size; (void)ws_size;
  const float* x   = (const float*)d_in[0];
  const float* g1  = (const float*)d_in[1];
  const float* be1 = (const float*)d_in[2];
  const float* W1  = (const float*)d_in[3];
  const float* b1  = (const float*)d_in[4];
  const float* g2  = (const float*)d_in[5];
  const float* be2 = (const float*)d_in[6];
  const float* W2  = (const float*)d_in[7];
  const float* b2  = (const float*)d_in[8];
  const int* tgt   = (const int*)d_in[9];
  const int* src   = (const int*)d_in[10];

  float* ws  = (float*)d_ws;
  float* out = (float*)d_out;

  float* P     = ws + WS_P;
  float* Q     = ws + WS_Q;
  float* cntT  = ws + WS_CNTT;
  int*   cntS  = (int*)(ws + WS_CNTS);
  float* stats = ws + WS_STATS;
  float* W1pT  = ws + WS_W1PT;
  float* b1p   = ws + WS_B1P;
  unsigned short* W2bf = (unsigned short*)(ws + WS_W2BF);
  float* b2p   = ws + WS_B2P;
  float* nbr   = out;  // scratch: overwritten by k_stats2's z + k_out_mfma

  k_zero  <<<dim3((NN + 255) / 256), dim3(256), 0, stream>>>(stats, cntS);
  k_cnt   <<<dim3(NE / 256),        dim3(256), 0, stream>>>(src, cntS);
  k_nbr   <<<dim3(NN),              dim3(Cc),  0, stream>>>(x, tgt, src, nbr, cntT);
  k_stats1<<<dim3(512),             dim3(512), 0, stream>>>(nbr, x, cntT, cntS, stats);
  k_fold1 <<<dim3(Cc),              dim3(C2),  0, stream>>>(W1, b1, g1, be1, stats, W1pT, b1p);
  k_pq    <<<dim3(NN / 32, 2),      dim3(256), 0, stream>>>(nbr, x, W1pT, P, Q);
  k_stats2<<<dim3(NE / 512),        dim3(512), 0, stream>>>(P, Q, b1p, tgt, src, stats,
                                                            (unsigned short*)out);
  k_fold2 <<<dim3(Cc),              dim3(Cc),  0, stream>>>(W2, b2, g2, be2, stats, W2bf, b2p);
  k_out_mfma<<<dim3(NE / 64),       dim3(256), 0, stream>>>((const unsigned short*)out,
                                                            W2bf, b2p, out);
}

// Round 17
// 307.290 us; speedup vs baseline: 1.0631x; 1.0631x over previous
//
#include <hip/hip_runtime.h>

#define NN 20000
#define NE 640000
#define Cc 128
#define C2 256
#define BN_EPS 1e-5f

typedef __attribute__((ext_vector_type(8))) short bf16x8;
typedef __attribute__((ext_vector_type(4))) float f32x4;

// ---- workspace layout (float offsets) ----
#define WS_P     0                      // [NN*Cc]
#define WS_Q     (NN*Cc)                // [NN*Cc]
#define WS_CNTT  (2*NN*Cc)              // [NN] float
#define WS_CNTS  (2*NN*Cc + NN)         // [NN] int
#define WS_STATS (2*NN*Cc + 2*NN)       // [768]: sum1[256], sq1[256], sum2[128], sq2[128]
#define WS_W1PT  (WS_STATS + 768)       // [256*128] transposed folded W1: [c][o]
#define WS_B1P   (WS_W1PT + C2*Cc)      // [128]
#define WS_W2BF  (WS_B1P + Cc)          // ushort[128*128] folded W2 bf16: [o][c]
#define WS_B2P   (WS_W2BF + Cc*Cc)      // [128]

// z (bf16) for edge e lives in the FIRST 256 B of out-row e's 512 B slot:
// ushort index e*256 + c. Written by k_stats2, read (then overwritten) by
// k_out_mfma's own wave -> no race (reads complete into regs before stores).

// fp32 -> bf16 round-to-nearest-even
static __device__ inline unsigned short f2bf(float f) {
  union { float f; unsigned u; } v; v.f = f;
  unsigned r = v.u + 0x7fffu + ((v.u >> 16) & 1u);
  return (unsigned short)(r >> 16);
}

__global__ void k_zero(float* __restrict__ stats, int* __restrict__ cntS) {
  int i = blockIdx.x * blockDim.x + threadIdx.x;
  if (i < 768) stats[i] = 0.0f;
  if (i < NN) cntS[i] = 0;
}

// one block (128 threads) per node: segment sum of x[src] over the node's
// contiguous (tgt sorted) edge range; 8 loads in flight. FUSED: src-histogram
// atomics for this node's edge range (replaces the separate k_cnt launch).
__global__ void k_nbr(const float* __restrict__ x, const int* __restrict__ tgt,
                      const int* __restrict__ src, float* __restrict__ nbr,
                      float* __restrict__ cntT, int* __restrict__ cntS) {
  int node = blockIdx.x;
  int a = 0, b = NE;
  while (a < b) { int m = (a + b) >> 1; if (tgt[m] < node) a = m + 1; else b = m; }
  int lo = a;
  b = NE;
  while (a < b) { int m = (a + b) >> 1; if (tgt[m] <= node) a = m + 1; else b = m; }
  int hi = a;
  int c = threadIdx.x;
  // fused k_cnt: each edge of this node counted exactly once block-wide
  for (int e = lo + c; e < hi; e += 128) atomicAdd(&cntS[src[e]], 1);
  float a0 = 0.f, a1 = 0.f, a2 = 0.f, a3 = 0.f;
  int e = lo;
  for (; e + 7 < hi; e += 8) {
    int s0 = src[e],     s1 = src[e + 1], s2 = src[e + 2], s3 = src[e + 3];
    int s4 = src[e + 4], s5 = src[e + 5], s6 = src[e + 6], s7 = src[e + 7];
    float v0 = x[(size_t)s0 * Cc + c], v1 = x[(size_t)s1 * Cc + c];
    float v2 = x[(size_t)s2 * Cc + c], v3 = x[(size_t)s3 * Cc + c];
    float v4 = x[(size_t)s4 * Cc + c], v5 = x[(size_t)s5 * Cc + c];
    float v6 = x[(size_t)s6 * Cc + c], v7 = x[(size_t)s7 * Cc + c];
    a0 += v0 + v4; a1 += v1 + v5; a2 += v2 + v6; a3 += v3 + v7;
  }
  for (; e + 3 < hi; e += 4) {
    int s0 = src[e], s1 = src[e + 1], s2 = src[e + 2], s3 = src[e + 3];
    a0 += x[(size_t)s0 * Cc + c];
    a1 += x[(size_t)s1 * Cc + c];
    a2 += x[(size_t)s2 * Cc + c];
    a3 += x[(size_t)s3 * Cc + c];
  }
  for (; e < hi; ++e) a0 += x[(size_t)src[e] * Cc + c];
  nbr[node * Cc + c] = (a0 + a1) + (a2 + a3);
  if (c == 0) cntT[node] = (float)(hi - lo);
}

// BN1 stats: count-weighted sums over nodes. 512 blocks x 512 threads.
__global__ __launch_bounds__(512) void k_stats1(const float* __restrict__ nbr,
                                                const float* __restrict__ x,
                                                const float* __restrict__ cntT,
                                                const int* __restrict__ cntS,
                                                float* __restrict__ stats) {
  __shared__ float ls[3][4][Cc];
  int c = threadIdx.x & 127;
  int y = threadIdx.x >> 7;       // 0..3
  float sa = 0.f, qa = 0.f, sb = 0.f, qb = 0.f;
  for (int t = blockIdx.x + y * 512; t < NN; t += 2048) {
    float ct = cntT[t];
    float cs = (float)cntS[t];
    float v1 = nbr[t * Cc + c];
    float v2 = x[t * Cc + c];
    sa += ct * v1; qa += ct * v1 * v1;
    sb += cs * v2; qb += cs * v2 * v2;
  }
  if (y) {
    ls[y - 1][0][c] = sa; ls[y - 1][1][c] = qa;
    ls[y - 1][2][c] = sb; ls[y - 1][3][c] = qb;
  }
  __syncthreads();
  if (!y) {
    #pragma unroll
    for (int j = 0; j < 3; ++j) {
      sa += ls[j][0][c]; qa += ls[j][1][c];
      sb += ls[j][2][c]; qb += ls[j][3][c];
    }
    atomicAdd(&stats[c], sa);
    atomicAdd(&stats[256 + c], qa);
    atomicAdd(&stats[128 + c], sb);
    atomicAdd(&stats[256 + 128 + c], qb);
  }
}

// fold BN1 into W1: W1pT[c][o] = W1[o][c]*a1[c];  b1p[o] = b1[o] + sum_c W1[o][c]*c1[c]
__global__ void k_fold1(const float* __restrict__ W1, const float* __restrict__ b1,
                        const float* __restrict__ g1, const float* __restrict__ be1,
                        const float* __restrict__ stats,
                        float* __restrict__ W1pT, float* __restrict__ b1p) {
  __shared__ float red[C2];
  int o = blockIdx.x, c = threadIdx.x;
  const float inv = 1.0f / (float)NE;
  float mu = stats[c] * inv;
  float var = stats[256 + c] * inv - mu * mu;
  float a = g1[c] * rsqrtf(var + BN_EPS);
  float cc = be1[c] - mu * a;
  float w = W1[o * C2 + c];
  W1pT[c * Cc + o] = w * a;
  red[c] = w * cc;
  __syncthreads();
  for (int s = 128; s > 0; s >>= 1) { if (c < s) red[c] += red[c + s]; __syncthreads(); }
  if (c == 0) b1p[o] = b1[o] + red[0];
}

// P = nbr_sum @ W1a'.T ; Q = x @ W1b'.T   (blockIdx.y selects half)
__global__ __launch_bounds__(256) void k_pq(const float* __restrict__ nbr,
                                            const float* __restrict__ x,
                                            const float* __restrict__ W1pT,
                                            float* __restrict__ P,
                                            float* __restrict__ Q) {
  __shared__ float Ar[32][128];
  const int half = blockIdx.y;
  const float* __restrict__ A = half ? x : nbr;
  float* __restrict__ Out = half ? Q : P;
  const float* __restrict__ Wt = W1pT + (half ? Cc * Cc : 0);  // [128 c][128 o]
  int tid = threadIdx.x;
  int r0 = blockIdx.x * 32;
  for (int i = tid; i < 32 * 128; i += 256) {
    int r = i >> 7, c = i & 127;
    Ar[r][c] = A[(r0 + r) * Cc + c];
  }
  __syncthreads();
  int tx = tid & 31, ty = tid >> 5;
  float acc[4][4] = {};
  #pragma unroll 4
  for (int c = 0; c < 128; ++c) {
    float4 w = *(const float4*)&Wt[c * Cc + tx * 4];
    float a0 = Ar[ty * 4 + 0][c], a1 = Ar[ty * 4 + 1][c];
    float a2 = Ar[ty * 4 + 2][c], a3 = Ar[ty * 4 + 3][c];
    acc[0][0] += a0 * w.x; acc[0][1] += a0 * w.y; acc[0][2] += a0 * w.z; acc[0][3] += a0 * w.w;
    acc[1][0] += a1 * w.x; acc[1][1] += a1 * w.y; acc[1][2] += a1 * w.z; acc[1][3] += a1 * w.w;
    acc[2][0] += a2 * w.x; acc[2][1] += a2 * w.y; acc[2][2] += a2 * w.z; acc[2][3] += a2 * w.w;
    acc[3][0] += a3 * w.x; acc[3][1] += a3 * w.y; acc[3][2] += a3 * w.z; acc[3][3] += a3 * w.w;
  }
  #pragma unroll
  for (int i = 0; i < 4; ++i) {
    int node = r0 + ty * 4 + i;
    float4 v = make_float4(acc[i][0], acc[i][1], acc[i][2], acc[i][3]);
    *(float4*)&Out[node * Cc + tx * 4] = v;
  }
}

// BN2 stats + z materialization. 1250 blocks x 512 threads, 8 octet-stripes
// x 64 channel-pairs (float2 gathers, ushort2 stores). XCD-aware BIJECTIVE
// block swizzle (m204): same-XCD blocks get contiguous 512-edge windows so
// each XCD's P working set is ~1.3 MB (L2-resident) instead of ~10 MB.
__global__ __launch_bounds__(512) void k_stats2(const float* __restrict__ P,
                                                const float* __restrict__ Q,
                                                const float* __restrict__ b1p,
                                                const int* __restrict__ tgt,
                                                const int* __restrict__ src,
                                                float* __restrict__ stats,
                                                unsigned short* __restrict__ zout) {
  __shared__ float s2[7][Cc], q2[7][Cc];
  const int nwg = NE / 512;                 // 1250
  const int q8 = nwg >> 3, r8 = nwg & 7;    // 156, 2
  int orig = blockIdx.x;
  int xcd = orig & 7, idx = orig >> 3;
  int bid = (xcd < r8 ? xcd * (q8 + 1) : r8 * (q8 + 1) + (xcd - r8) * q8) + idx;
  int cp = threadIdx.x & 63;      // channel pair 0..63
  int y = threadIdx.x >> 6;       // stripe 0..7
  int c0 = cp * 2;
  int e0 = bid * 512;
  float2 b = *(const float2*)&b1p[c0];
  float s0 = 0.f, s1 = 0.f, q0 = 0.f, q1 = 0.f;
  for (int e = e0 + y * 8; e < e0 + 512; e += 64) {
    int t[8], sr[8];
    #pragma unroll
    for (int j = 0; j < 8; ++j) { t[j] = tgt[e + j]; sr[j] = src[e + j]; }
    float2 pv[8], qv[8];
    #pragma unroll
    for (int j = 0; j < 8; ++j) pv[j] = *(const float2*)&P[(size_t)t[j] * Cc + c0];
    #pragma unroll
    for (int j = 0; j < 8; ++j) qv[j] = *(const float2*)&Q[(size_t)sr[j] * Cc + c0];
    #pragma unroll
    for (int j = 0; j < 8; ++j) {
      float z0 = fmaxf(pv[j].x + qv[j].x + b.x, 0.f);
      float z1 = fmaxf(pv[j].y + qv[j].y + b.y, 0.f);
      ushort2 zz; zz.x = f2bf(z0); zz.y = f2bf(z1);
      *(ushort2*)&zout[(size_t)(e + j) * 256 + c0] = zz;
      s0 += z0; s1 += z1; q0 += z0 * z0; q1 += z1 * z1;
    }
  }
  if (y) { s2[y - 1][c0] = s0; s2[y - 1][c0 + 1] = s1;
           q2[y - 1][c0] = q0; q2[y - 1][c0 + 1] = q1; }
  __syncthreads();
  if (!y) {
    #pragma unroll
    for (int j = 0; j < 7; ++j) {
      s0 += s2[j][c0]; s1 += s2[j][c0 + 1];
      q0 += q2[j][c0]; q1 += q2[j][c0 + 1];
    }
    atomicAdd(&stats[512 + c0], s0);
    atomicAdd(&stats[512 + c0 + 1], s1);
    atomicAdd(&stats[640 + c0], q0);
    atomicAdd(&stats[640 + c0 + 1], q1);
  }
}

// fold BN2 into W2, emit bf16 [o][c] weights + fp32 bias
__global__ void k_fold2(const float* __restrict__ W2, const float* __restrict__ b2,
                        const float* __restrict__ g2, const float* __restrict__ be2,
                        const float* __restrict__ stats,
                        unsigned short* __restrict__ W2bf, float* __restrict__ b2p) {
  __shared__ float red[Cc];
  int o = blockIdx.x, c = threadIdx.x;
  const float inv = 1.0f / (float)NE;
  float mu = stats[512 + c] * inv;
  float var = stats[640 + c] * inv - mu * mu;
  float a = g2[c] * rsqrtf(var + BN_EPS);
  float cc = be2[c] - mu * a;
  float w = W2[o * Cc + c];
  W2bf[o * Cc + c] = f2bf(w * a);
  red[c] = w * cc;
  __syncthreads();
  for (int s = 64; s > 0; s >>= 1) { if (c < s) red[c] += red[c + s]; __syncthreads(); }
  if (c == 0) b2p[o] = b2[o] + red[0];
}

// out[e][o] = relu( z[e]@W2' + b2' ): pure streaming bf16 MFMA GEMM.
// Operand-SWAPPED (A=W rows=outs, B=z cols=edges): 8 float4 stores per lane.
// z read from out-row slot into regs before stores (safe in-place overwrite).
#define WPAD 136
__global__ __launch_bounds__(256) void k_out_mfma(const unsigned short* __restrict__ zin,
                                                  const unsigned short* __restrict__ W2bf,
                                                  const float* __restrict__ b2p,
                                                  float* __restrict__ out) {
  __shared__ unsigned short Wl[128 * WPAD];  // 34816 B -> 4 blocks/CU
  int tid = threadIdx.x;
  int e0 = blockIdx.x * 64;

  // stage folded-bf16 W2 [o][c] -> LDS (coalesced 16B loads)
  for (int i = tid; i < 2048; i += 256) {
    int row = i >> 4, col = (i & 15) * 8;
    *(bf16x8*)&Wl[row * WPAD + col] = *(const bf16x8*)&W2bf[row * Cc + col];
  }

  int w = tid >> 6, l = tid & 63;
  int la = l & 15, kb = l >> 4;
  int e = e0 + w * 16 + la;

  // load all 4 B-fragments (full z row slice) into registers up front
  bf16x8 zfr[4];
  #pragma unroll
  for (int kk = 0; kk < 4; ++kk)
    zfr[kk] = *(const bf16x8*)&zin[(size_t)e * 256 + kk * 32 + kb * 8];
  __syncthreads();

  f32x4 acc[8];
  #pragma unroll
  for (int n = 0; n < 8; ++n) acc[n] = (f32x4){0.f, 0.f, 0.f, 0.f};

  #pragma unroll
  for (int kk = 0; kk < 4; ++kk) {        // K = 128 in 4 steps of 32
    #pragma unroll
    for (int n = 0; n < 8; ++n) {         // 8 out-tiles of 16
      bf16x8 wa = *(const bf16x8*)&Wl[(n * 16 + la) * WPAD + kk * 32 + kb * 8];
      acc[n] = __builtin_amdgcn_mfma_f32_16x16x32_bf16(wa, zfr[kk], acc[n], 0, 0, 0);
    }
  }

  // D layout: col(edge) = la, row(out) = kb*4 + r -> contiguous float4 per lane
  #pragma unroll
  for (int n = 0; n < 8; ++n) {
    int o0 = n * 16 + kb * 4;
    float4 bb = *(const float4*)&b2p[o0];
    float4 v;
    v.x = fmaxf(acc[n][0] + bb.x, 0.f);
    v.y = fmaxf(acc[n][1] + bb.y, 0.f);
    v.z = fmaxf(acc[n][2] + bb.z, 0.f);
    v.w = fmaxf(acc[n][3] + bb.w, 0.f);
    *(float4*)&out[(size_t)e * Cc + o0] = v;
  }
}

extern "C" void kernel_launch(void* const* d_in, const int* in_sizes, int n_in,
                              void* d_out, int out_size, void* d_ws, size_t ws_size,
                              hipStream_t stream) {
  (void)in_sizes; (void)n_in; (void)out_size; (void)ws_size;
  const float* x   = (const float*)d_in[0];
  const float* g1  = (const float*)d_in[1];
  const float* be1 = (const float*)d_in[2];
  const float* W1  = (const float*)d_in[3];
  const float* b1  = (const float*)d_in[4];
  const float* g2  = (const float*)d_in[5];
  const float* be2 = (const float*)d_in[6];
  const float* W2  = (const float*)d_in[7];
  const float* b2  = (const float*)d_in[8];
  const int* tgt   = (const int*)d_in[9];
  const int* src   = (const int*)d_in[10];

  float* ws  = (float*)d_ws;
  float* out = (float*)d_out;

  float* P     = ws + WS_P;
  float* Q     = ws + WS_Q;
  float* cntT  = ws + WS_CNTT;
  int*   cntS  = (int*)(ws + WS_CNTS);
  float* stats = ws + WS_STATS;
  float* W1pT  = ws + WS_W1PT;
  float* b1p   = ws + WS_B1P;
  unsigned short* W2bf = (unsigned short*)(ws + WS_W2BF);
  float* b2p   = ws + WS_B2P;
  float* nbr   = out;  // scratch: overwritten by k_stats2's z + k_out_mfma

  k_zero  <<<dim3((NN + 255) / 256), dim3(256), 0, stream>>>(stats, cntS);
  k_nbr   <<<dim3(NN),              dim3(Cc),  0, stream>>>(x, tgt, src, nbr, cntT, cntS);
  k_stats1<<<dim3(512),             dim3(512), 0, stream>>>(nbr, x, cntT, cntS, stats);
  k_fold1 <<<dim3(Cc),              dim3(C2),  0, stream>>>(W1, b1, g1, be1, stats, W1pT, b1p);
  k_pq    <<<dim3(NN / 32, 2),      dim3(256), 0, stream>>>(nbr, x, W1pT, P, Q);
  k_stats2<<<dim3(NE / 512),        dim3(512), 0, stream>>>(P, Q, b1p, tgt, src, stats,
                                                            (unsigned short*)out);
  k_fold2 <<<dim3(Cc),              dim3(Cc),  0, stream>>>(W2, b2, g2, be2, stats, W2bf, b2p);
  k_out_mfma<<<dim3(NE / 64),       dim3(256), 0, stream>>>((const unsigned short*)out,
                                                            W2bf, b2p, out);
}

// Round 18
// 298.594 us; speedup vs baseline: 1.0941x; 1.0291x over previous
//
#include <hip/hip_runtime.h>

#define NN 20000
#define NE 640000
#define Cc 128
#define C2 256
#define BN_EPS 1e-5f

typedef __attribute__((ext_vector_type(8))) short bf16x8;
typedef __attribute__((ext_vector_type(4))) float f32x4;

// ---- workspace layout (float offsets; P/Q now bf16, use half their slot) ----
#define WS_P     0                      // ushort[NN*Cc] bf16 P
#define WS_Q     (NN*Cc)                // ushort[NN*Cc] bf16 Q
#define WS_CNTT  (2*NN*Cc)              // [NN] float
#define WS_CNTS  (2*NN*Cc + NN)         // [NN] int
#define WS_STATS (2*NN*Cc + 2*NN)       // [768]
#define WS_W1PT  (WS_STATS + 768)       // [256*128] folded W1 [c][o] fp32
#define WS_B1P   (WS_W1PT + C2*Cc)      // [128]
#define WS_W2BF  (WS_B1P + Cc)          // ushort[128*128] folded W2 bf16 [o][c]
#define WS_B2P   (WS_W2BF + Cc*Cc)      // [128]

// z (bf16) for edge e lives in the FIRST 256 B of out-row e's 512 B slot.

// fp32 -> bf16 round-to-nearest-even
static __device__ inline unsigned short f2bf(float f) {
  union { float f; unsigned u; } v; v.f = f;
  unsigned r = v.u + 0x7fffu + ((v.u >> 16) & 1u);
  return (unsigned short)(r >> 16);
}
static __device__ inline float bf2f(unsigned short h) {
  union { unsigned u; float f; } v; v.u = (unsigned)h << 16; return v.f;
}

__global__ void k_zero(float* __restrict__ stats, int* __restrict__ cntS) {
  int i = blockIdx.x * blockDim.x + threadIdx.x;
  if (i < 768) stats[i] = 0.0f;
  if (i < NN) cntS[i] = 0;
}

// one block (128 threads) per node: segment sum + fused src-histogram.
__global__ void k_nbr(const float* __restrict__ x, const int* __restrict__ tgt,
                      const int* __restrict__ src, float* __restrict__ nbr,
                      float* __restrict__ cntT, int* __restrict__ cntS) {
  int node = blockIdx.x;
  int a = 0, b = NE;
  while (a < b) { int m = (a + b) >> 1; if (tgt[m] < node) a = m + 1; else b = m; }
  int lo = a;
  b = NE;
  while (a < b) { int m = (a + b) >> 1; if (tgt[m] <= node) a = m + 1; else b = m; }
  int hi = a;
  int c = threadIdx.x;
  for (int e = lo + c; e < hi; e += 128) atomicAdd(&cntS[src[e]], 1);
  float a0 = 0.f, a1 = 0.f, a2 = 0.f, a3 = 0.f;
  int e = lo;
  for (; e + 7 < hi; e += 8) {
    int s0 = src[e],     s1 = src[e + 1], s2 = src[e + 2], s3 = src[e + 3];
    int s4 = src[e + 4], s5 = src[e + 5], s6 = src[e + 6], s7 = src[e + 7];
    float v0 = x[(size_t)s0 * Cc + c], v1 = x[(size_t)s1 * Cc + c];
    float v2 = x[(size_t)s2 * Cc + c], v3 = x[(size_t)s3 * Cc + c];
    float v4 = x[(size_t)s4 * Cc + c], v5 = x[(size_t)s5 * Cc + c];
    float v6 = x[(size_t)s6 * Cc + c], v7 = x[(size_t)s7 * Cc + c];
    a0 += v0 + v4; a1 += v1 + v5; a2 += v2 + v6; a3 += v3 + v7;
  }
  for (; e + 3 < hi; e += 4) {
    int s0 = src[e], s1 = src[e + 1], s2 = src[e + 2], s3 = src[e + 3];
    a0 += x[(size_t)s0 * Cc + c];
    a1 += x[(size_t)s1 * Cc + c];
    a2 += x[(size_t)s2 * Cc + c];
    a3 += x[(size_t)s3 * Cc + c];
  }
  for (; e < hi; ++e) a0 += x[(size_t)src[e] * Cc + c];
  nbr[node * Cc + c] = (a0 + a1) + (a2 + a3);
  if (c == 0) cntT[node] = (float)(hi - lo);
}

// BN1 stats: 512 blocks x 512 threads.
__global__ __launch_bounds__(512) void k_stats1(const float* __restrict__ nbr,
                                                const float* __restrict__ x,
                                                const float* __restrict__ cntT,
                                                const int* __restrict__ cntS,
                                                float* __restrict__ stats) {
  __shared__ float ls[3][4][Cc];
  int c = threadIdx.x & 127;
  int y = threadIdx.x >> 7;
  float sa = 0.f, qa = 0.f, sb = 0.f, qb = 0.f;
  for (int t = blockIdx.x + y * 512; t < NN; t += 2048) {
    float ct = cntT[t];
    float cs = (float)cntS[t];
    float v1 = nbr[t * Cc + c];
    float v2 = x[t * Cc + c];
    sa += ct * v1; qa += ct * v1 * v1;
    sb += cs * v2; qb += cs * v2 * v2;
  }
  if (y) {
    ls[y - 1][0][c] = sa; ls[y - 1][1][c] = qa;
    ls[y - 1][2][c] = sb; ls[y - 1][3][c] = qb;
  }
  __syncthreads();
  if (!y) {
    #pragma unroll
    for (int j = 0; j < 3; ++j) {
      sa += ls[j][0][c]; qa += ls[j][1][c];
      sb += ls[j][2][c]; qb += ls[j][3][c];
    }
    atomicAdd(&stats[c], sa);
    atomicAdd(&stats[256 + c], qa);
    atomicAdd(&stats[128 + c], sb);
    atomicAdd(&stats[256 + 128 + c], qb);
  }
}

// fold BN1 into W1
__global__ void k_fold1(const float* __restrict__ W1, const float* __restrict__ b1,
                        const float* __restrict__ g1, const float* __restrict__ be1,
                        const float* __restrict__ stats,
                        float* __restrict__ W1pT, float* __restrict__ b1p) {
  __shared__ float red[C2];
  int o = blockIdx.x, c = threadIdx.x;
  const float inv = 1.0f / (float)NE;
  float mu = stats[c] * inv;
  float var = stats[256 + c] * inv - mu * mu;
  float a = g1[c] * rsqrtf(var + BN_EPS);
  float cc = be1[c] - mu * a;
  float w = W1[o * C2 + c];
  W1pT[c * Cc + o] = w * a;
  red[c] = w * cc;
  __syncthreads();
  for (int s = 128; s > 0; s >>= 1) { if (c < s) red[c] += red[c + s]; __syncthreads(); }
  if (c == 0) b1p[o] = b1[o] + red[0];
}

// P = nbr@W1a'.T ; Q = x@W1b'.T  -> bf16 tables (halves gather footprint).
__global__ __launch_bounds__(256) void k_pq(const float* __restrict__ nbr,
                                            const float* __restrict__ x,
                                            const float* __restrict__ W1pT,
                                            unsigned short* __restrict__ P,
                                            unsigned short* __restrict__ Q) {
  __shared__ float Ar[32][128];
  const int half = blockIdx.y;
  const float* __restrict__ A = half ? x : nbr;
  unsigned short* __restrict__ Out = half ? Q : P;
  const float* __restrict__ Wt = W1pT + (half ? Cc * Cc : 0);
  int tid = threadIdx.x;
  int r0 = blockIdx.x * 32;
  for (int i = tid; i < 32 * 128; i += 256) {
    int r = i >> 7, c = i & 127;
    Ar[r][c] = A[(r0 + r) * Cc + c];
  }
  __syncthreads();
  int tx = tid & 31, ty = tid >> 5;
  float acc[4][4] = {};
  #pragma unroll 4
  for (int c = 0; c < 128; ++c) {
    float4 w = *(const float4*)&Wt[c * Cc + tx * 4];
    float a0 = Ar[ty * 4 + 0][c], a1 = Ar[ty * 4 + 1][c];
    float a2 = Ar[ty * 4 + 2][c], a3 = Ar[ty * 4 + 3][c];
    acc[0][0] += a0 * w.x; acc[0][1] += a0 * w.y; acc[0][2] += a0 * w.z; acc[0][3] += a0 * w.w;
    acc[1][0] += a1 * w.x; acc[1][1] += a1 * w.y; acc[1][2] += a1 * w.z; acc[1][3] += a1 * w.w;
    acc[2][0] += a2 * w.x; acc[2][1] += a2 * w.y; acc[2][2] += a2 * w.z; acc[2][3] += a2 * w.w;
    acc[3][0] += a3 * w.x; acc[3][1] += a3 * w.y; acc[3][2] += a3 * w.z; acc[3][3] += a3 * w.w;
  }
  #pragma unroll
  for (int i = 0; i < 4; ++i) {
    int node = r0 + ty * 4 + i;
    ushort4 v;
    v.x = f2bf(acc[i][0]); v.y = f2bf(acc[i][1]);
    v.z = f2bf(acc[i][2]); v.w = f2bf(acc[i][3]);
    *(ushort4*)&Out[node * Cc + tx * 4] = v;
  }
}

// BN2 stats + z materialization; bf16 P/Q gathers (ushort2), XCD swizzle.
__global__ __launch_bounds__(512) void k_stats2(const unsigned short* __restrict__ P,
                                                const unsigned short* __restrict__ Q,
                                                const float* __restrict__ b1p,
                                                const int* __restrict__ tgt,
                                                const int* __restrict__ src,
                                                float* __restrict__ stats,
                                                unsigned short* __restrict__ zout) {
  __shared__ float s2[7][Cc], q2[7][Cc];
  const int nwg = NE / 512;                 // 1250
  const int q8 = nwg >> 3, r8 = nwg & 7;    // 156, 2
  int orig = blockIdx.x;
  int xcd = orig & 7, idx = orig >> 3;
  int bid = (xcd < r8 ? xcd * (q8 + 1) : r8 * (q8 + 1) + (xcd - r8) * q8) + idx;
  int cp = threadIdx.x & 63;
  int y = threadIdx.x >> 6;
  int c0 = cp * 2;
  int e0 = bid * 512;
  float2 b = *(const float2*)&b1p[c0];
  float s0 = 0.f, s1 = 0.f, q0 = 0.f, q1 = 0.f;
  for (int e = e0 + y * 8; e < e0 + 512; e += 64) {
    int t[8], sr[8];
    #pragma unroll
    for (int j = 0; j < 8; ++j) { t[j] = tgt[e + j]; sr[j] = src[e + j]; }
    ushort2 pv[8], qv[8];
    #pragma unroll
    for (int j = 0; j < 8; ++j) pv[j] = *(const ushort2*)&P[(size_t)t[j] * Cc + c0];
    #pragma unroll
    for (int j = 0; j < 8; ++j) qv[j] = *(const ushort2*)&Q[(size_t)sr[j] * Cc + c0];
    #pragma unroll
    for (int j = 0; j < 8; ++j) {
      float z0 = fmaxf(bf2f(pv[j].x) + bf2f(qv[j].x) + b.x, 0.f);
      float z1 = fmaxf(bf2f(pv[j].y) + bf2f(qv[j].y) + b.y, 0.f);
      ushort2 zz; zz.x = f2bf(z0); zz.y = f2bf(z1);
      *(ushort2*)&zout[(size_t)(e + j) * 256 + c0] = zz;
      s0 += z0; s1 += z1; q0 += z0 * z0; q1 += z1 * z1;
    }
  }
  if (y) { s2[y - 1][c0] = s0; s2[y - 1][c0 + 1] = s1;
           q2[y - 1][c0] = q0; q2[y - 1][c0 + 1] = q1; }
  __syncthreads();
  if (!y) {
    #pragma unroll
    for (int j = 0; j < 7; ++j) {
      s0 += s2[j][c0]; s1 += s2[j][c0 + 1];
      q0 += q2[j][c0]; q1 += q2[j][c0 + 1];
    }
    atomicAdd(&stats[512 + c0], s0);
    atomicAdd(&stats[512 + c0 + 1], s1);
    atomicAdd(&stats[640 + c0], q0);
    atomicAdd(&stats[640 + c0 + 1], q1);
  }
}

// fold BN2 into W2, emit bf16 [o][c] weights + fp32 bias
__global__ void k_fold2(const float* __restrict__ W2, const float* __restrict__ b2,
                        const float* __restrict__ g2, const float* __restrict__ be2,
                        const float* __restrict__ stats,
                        unsigned short* __restrict__ W2bf, float* __restrict__ b2p) {
  __shared__ float red[Cc];
  int o = blockIdx.x, c = threadIdx.x;
  const float inv = 1.0f / (float)NE;
  float mu = stats[512 + c] * inv;
  float var = stats[640 + c] * inv - mu * mu;
  float a = g2[c] * rsqrtf(var + BN_EPS);
  float cc = be2[c] - mu * a;
  float w = W2[o * Cc + c];
  W2bf[o * Cc + c] = f2bf(w * a);
  red[c] = w * cc;
  __syncthreads();
  for (int s = 64; s > 0; s >>= 1) { if (c < s) red[c] += red[c + s]; __syncthreads(); }
  if (c == 0) b2p[o] = b2[o] + red[0];
}

// out[e][o] = relu( z[e]@W2' + b2' ): streaming bf16 MFMA GEMM, operand-swapped.
#define WPAD 136
__global__ __launch_bounds__(256) void k_out_mfma(const unsigned short* __restrict__ zin,
                                                  const unsigned short* __restrict__ W2bf,
                                                  const float* __restrict__ b2p,
                                                  float* __restrict__ out) {
  __shared__ unsigned short Wl[128 * WPAD];
  int tid = threadIdx.x;
  int e0 = blockIdx.x * 64;

  for (int i = tid; i < 2048; i += 256) {
    int row = i >> 4, col = (i & 15) * 8;
    *(bf16x8*)&Wl[row * WPAD + col] = *(const bf16x8*)&W2bf[row * Cc + col];
  }

  int w = tid >> 6, l = tid & 63;
  int la = l & 15, kb = l >> 4;
  int e = e0 + w * 16 + la;

  bf16x8 zfr[4];
  #pragma unroll
  for (int kk = 0; kk < 4; ++kk)
    zfr[kk] = *(const bf16x8*)&zin[(size_t)e * 256 + kk * 32 + kb * 8];
  __syncthreads();

  f32x4 acc[8];
  #pragma unroll
  for (int n = 0; n < 8; ++n) acc[n] = (f32x4){0.f, 0.f, 0.f, 0.f};

  #pragma unroll
  for (int kk = 0; kk < 4; ++kk) {
    #pragma unroll
    for (int n = 0; n < 8; ++n) {
      bf16x8 wa = *(const bf16x8*)&Wl[(n * 16 + la) * WPAD + kk * 32 + kb * 8];
      acc[n] = __builtin_amdgcn_mfma_f32_16x16x32_bf16(wa, zfr[kk], acc[n], 0, 0, 0);
    }
  }

  #pragma unroll
  for (int n = 0; n < 8; ++n) {
    int o0 = n * 16 + kb * 4;
    float4 bb = *(const float4*)&b2p[o0];
    float4 v;
    v.x = fmaxf(acc[n][0] + bb.x, 0.f);
    v.y = fmaxf(acc[n][1] + bb.y, 0.f);
    v.z = fmaxf(acc[n][2] + bb.z, 0.f);
    v.w = fmaxf(acc[n][3] + bb.w, 0.f);
    *(float4*)&out[(size_t)e * Cc + o0] = v;
  }
}

extern "C" void kernel_launch(void* const* d_in, const int* in_sizes, int n_in,
                              void* d_out, int out_size, void* d_ws, size_t ws_size,
                              hipStream_t stream) {
  (void)in_sizes; (void)n_in; (void)out_size; (void)ws_size;
  const float* x   = (const float*)d_in[0];
  const float* g1  = (const float*)d_in[1];
  const float* be1 = (const float*)d_in[2];
  const float* W1  = (const float*)d_in[3];
  const float* b1  = (const float*)d_in[4];
  const float* g2  = (const float*)d_in[5];
  const float* be2 = (const float*)d_in[6];
  const float* W2  = (const float*)d_in[7];
  const float* b2  = (const float*)d_in[8];
  const int* tgt   = (const int*)d_in[9];
  const int* src   = (const int*)d_in[10];

  float* ws  = (float*)d_ws;
  float* out = (float*)d_out;

  unsigned short* P = (unsigned short*)(ws + WS_P);
  unsigned short* Q = (unsigned short*)(ws + WS_Q);
  float* cntT  = ws + WS_CNTT;
  int*   cntS  = (int*)(ws + WS_CNTS);
  float* stats = ws + WS_STATS;
  float* W1pT  = ws + WS_W1PT;
  float* b1p   = ws + WS_B1P;
  unsigned short* W2bf = (unsigned short*)(ws + WS_W2BF);
  float* b2p   = ws + WS_B2P;
  float* nbr   = out;  // scratch: overwritten by k_stats2's z + k_out_mfma

  k_zero  <<<dim3((NN + 255) / 256), dim3(256), 0, stream>>>(stats, cntS);
  k_nbr   <<<dim3(NN),              dim3(Cc),  0, stream>>>(x, tgt, src, nbr, cntT, cntS);
  k_stats1<<<dim3(512),             dim3(512), 0, stream>>>(nbr, x, cntT, cntS, stats);
  k_fold1 <<<dim3(Cc),              dim3(C2),  0, stream>>>(W1, b1, g1, be1, stats, W1pT, b1p);
  k_pq    <<<dim3(NN / 32, 2),      dim3(256), 0, stream>>>(nbr, x, W1pT, P, Q);
  k_stats2<<<dim3(NE / 512),        dim3(512), 0, stream>>>(P, Q, b1p, tgt, src, stats,
                                                            (unsigned short*)out);
  k_fold2 <<<dim3(Cc),              dim3(Cc),  0, stream>>>(W2, b2, g2, be2, stats, W2bf, b2p);
  k_out_mfma<<<dim3(NE / 64),       dim3(256), 0, stream>>>((const unsigned short*)out,
                                                            W2bf, b2p, out);
}

// Round 20
// 281.034 us; speedup vs baseline: 1.1625x; 1.0625x over previous
//
#include <hip/hip_runtime.h>

#define NN 20000
#define NE 640000
#define Cc 128
#define C2 256
#define BN_EPS 1e-5f

typedef __attribute__((ext_vector_type(8))) short bf16x8;
typedef __attribute__((ext_vector_type(4))) float f32x4;

// ---- workspace layout (float offsets) ----
// P slot [0, NN*Cc): bf16 P uses first half; bf16 xbf packed in SECOND half.
#define WS_P     0                      // ushort[NN*Cc] bf16 P (floats 0..NN*Cc/2)
#define WS_XBF   (NN*Cc/2)              // ushort[NN*Cc] bf16 x (floats NN*Cc/2..NN*Cc)
#define WS_Q     (NN*Cc)                // ushort[NN*Cc] bf16 Q (first half of slot)
#define WS_CNTT  (2*NN*Cc)              // [NN] float
#define WS_CNTS  (2*NN*Cc + NN)         // [NN] int
#define WS_STATS (2*NN*Cc + 2*NN)       // [768]
#define WS_W1BF  (WS_STATS + 768)       // ushort[2*128*128] folded W1 bf16 [half][o][c] (in old W1PT slot)
#define WS_B1P   (WS_W1BF + C2*Cc)      // [128]
#define WS_W2BF  (WS_B1P + Cc)          // ushort[128*128] folded W2 bf16 [o][c]
#define WS_B2P   (WS_W2BF + Cc*Cc)      // [128]

// z (bf16) for edge e lives in the FIRST 256 B of out-row e's 512 B slot.
// nbr (bf16, [NN][Cc]) lives at the start of d_out until k_pq consumes it
// (stream-ordered before k_stats2's z-writes overwrite that region).

static __device__ inline unsigned short f2bf(float f) {
  union { float f; unsigned u; } v; v.f = f;
  unsigned r = v.u + 0x7fffu + ((v.u >> 16) & 1u);
  return (unsigned short)(r >> 16);
}
static __device__ inline float bf2f(unsigned short h) {
  union { unsigned u; float f; } v; v.u = (unsigned)h << 16; return v.f;
}

__global__ void k_zero(float* __restrict__ stats, int* __restrict__ cntS) {
  int i = blockIdx.x * blockDim.x + threadIdx.x;
  if (i < 768) stats[i] = 0.0f;
  if (i < NN) cntS[i] = 0;
}

// cast x -> bf16 table (5.12 MB): 8 elems/thread
__global__ __launch_bounds__(256) void k_cast(const float* __restrict__ x,
                                              unsigned short* __restrict__ xbf) {
  int i = (blockIdx.x * 256 + threadIdx.x) * 8;
  float4 v0 = *(const float4*)&x[i];
  float4 v1 = *(const float4*)&x[i + 4];
  bf16x8 o;
  o[0] = (short)f2bf(v0.x); o[1] = (short)f2bf(v0.y);
  o[2] = (short)f2bf(v0.z); o[3] = (short)f2bf(v0.w);
  o[4] = (short)f2bf(v1.x); o[5] = (short)f2bf(v1.y);
  o[6] = (short)f2bf(v1.z); o[7] = (short)f2bf(v1.w);
  *(bf16x8*)&xbf[i] = o;
}

// one block (128 threads) per node: segment sum of bf16 x over the node's
// edge range (8-deep ILP) + fused src-histogram. nbr written bf16.
__global__ void k_nbr(const unsigned short* __restrict__ xbf, const int* __restrict__ tgt,
                      const int* __restrict__ src, unsigned short* __restrict__ nbr,
                      float* __restrict__ cntT, int* __restrict__ cntS) {
  int node = blockIdx.x;
  int a = 0, b = NE;
  while (a < b) { int m = (a + b) >> 1; if (tgt[m] < node) a = m + 1; else b = m; }
  int lo = a;
  b = NE;
  while (a < b) { int m = (a + b) >> 1; if (tgt[m] <= node) a = m + 1; else b = m; }
  int hi = a;
  int c = threadIdx.x;
  for (int e = lo + c; e < hi; e += 128) atomicAdd(&cntS[src[e]], 1);
  float a0 = 0.f, a1 = 0.f, a2 = 0.f, a3 = 0.f;
  int e = lo;
  for (; e + 7 < hi; e += 8) {
    int s0 = src[e],     s1 = src[e + 1], s2 = src[e + 2], s3 = src[e + 3];
    int s4 = src[e + 4], s5 = src[e + 5], s6 = src[e + 6], s7 = src[e + 7];
    float v0 = bf2f(xbf[(size_t)s0 * Cc + c]), v1 = bf2f(xbf[(size_t)s1 * Cc + c]);
    float v2 = bf2f(xbf[(size_t)s2 * Cc + c]), v3 = bf2f(xbf[(size_t)s3 * Cc + c]);
    float v4 = bf2f(xbf[(size_t)s4 * Cc + c]), v5 = bf2f(xbf[(size_t)s5 * Cc + c]);
    float v6 = bf2f(xbf[(size_t)s6 * Cc + c]), v7 = bf2f(xbf[(size_t)s7 * Cc + c]);
    a0 += v0 + v4; a1 += v1 + v5; a2 += v2 + v6; a3 += v3 + v7;
  }
  for (; e < hi; ++e) a0 += bf2f(xbf[(size_t)src[e] * Cc + c]);
  nbr[(size_t)node * Cc + c] = f2bf((a0 + a1) + (a2 + a3));
  if (c == 0) cntT[node] = (float)(hi - lo);
}

// BN1 stats from bf16 tables. 512 blocks x 512 threads.
__global__ __launch_bounds__(512) void k_stats1(const unsigned short* __restrict__ nbr,
                                                const unsigned short* __restrict__ xbf,
                                                const float* __restrict__ cntT,
                                                const int* __restrict__ cntS,
                                                float* __restrict__ stats) {
  __shared__ float ls[3][4][Cc];
  int c = threadIdx.x & 127;
  int y = threadIdx.x >> 7;
  float sa = 0.f, qa = 0.f, sb = 0.f, qb = 0.f;
  for (int t = blockIdx.x + y * 512; t < NN; t += 2048) {
    float ct = cntT[t];
    float cs = (float)cntS[t];
    float v1 = bf2f(nbr[(size_t)t * Cc + c]);
    float v2 = bf2f(xbf[(size_t)t * Cc + c]);
    sa += ct * v1; qa += ct * v1 * v1;
    sb += cs * v2; qb += cs * v2 * v2;
  }
  if (y) {
    ls[y - 1][0][c] = sa; ls[y - 1][1][c] = qa;
    ls[y - 1][2][c] = sb; ls[y - 1][3][c] = qb;
  }
  __syncthreads();
  if (!y) {
    #pragma unroll
    for (int j = 0; j < 3; ++j) {
      sa += ls[j][0][c]; qa += ls[j][1][c];
      sb += ls[j][2][c]; qb += ls[j][3][c];
    }
    atomicAdd(&stats[c], sa);
    atomicAdd(&stats[256 + c], qa);
    atomicAdd(&stats[128 + c], sb);
    atomicAdd(&stats[256 + 128 + c], qb);
  }
}

// fold BN1 into W1 -> bf16 [half][o][c] + fp32 b1p
__global__ void k_fold1(const float* __restrict__ W1, const float* __restrict__ b1,
                        const float* __restrict__ g1, const float* __restrict__ be1,
                        const float* __restrict__ stats,
                        unsigned short* __restrict__ W1bf, float* __restrict__ b1p) {
  __shared__ float red[C2];
  int o = blockIdx.x, c = threadIdx.x;
  const float inv = 1.0f / (float)NE;
  float mu = stats[c] * inv;
  float var = stats[256 + c] * inv - mu * mu;
  float a = g1[c] * rsqrtf(var + BN_EPS);
  float cc = be1[c] - mu * a;
  float w = W1[o * C2 + c];
  W1bf[(size_t)(c >> 7) * Cc * Cc + o * Cc + (c & 127)] = f2bf(w * a);
  red[c] = w * cc;
  __syncthreads();
  for (int s = 128; s > 0; s >>= 1) { if (c < s) red[c] += red[c + s]; __syncthreads(); }
  if (c == 0) b1p[o] = b1[o] + red[0];
}

// P = nbr@W1a'.T ; Q = x@W1b'.T  via bf16 MFMA (k_out pattern, swapped ops).
// 64 nodes x 128 outs per block; tail block guarded (NN % 64 != 0).
#define WPAD 136
__global__ __launch_bounds__(256) void k_pq(const unsigned short* __restrict__ nbr,
                                            const unsigned short* __restrict__ xbf,
                                            const unsigned short* __restrict__ W1bf,
                                            unsigned short* __restrict__ P,
                                            unsigned short* __restrict__ Q) {
  __shared__ unsigned short Wl[128 * WPAD];
  const int half = blockIdx.y;
  const unsigned short* __restrict__ A = half ? xbf : nbr;
  unsigned short* __restrict__ Out = half ? Q : P;
  const unsigned short* __restrict__ Wt = W1bf + (size_t)half * Cc * Cc;
  int tid = threadIdx.x;
  int n0 = blockIdx.x * 64;

  for (int i = tid; i < 2048; i += 256) {
    int row = i >> 4, col = (i & 15) * 8;
    *(bf16x8*)&Wl[row * WPAD + col] = *(const bf16x8*)&Wt[row * Cc + col];
  }

  int w = tid >> 6, l = tid & 63;
  int la = l & 15, kb = l >> 4;
  int node = n0 + w * 16 + la;
  int ld = node < NN ? node : NN - 1;

  bf16x8 zfr[4];
  #pragma unroll
  for (int kk = 0; kk < 4; ++kk)
    zfr[kk] = *(const bf16x8*)&A[(size_t)ld * Cc + kk * 32 + kb * 8];
  __syncthreads();

  f32x4 acc[8];
  #pragma unroll
  for (int n = 0; n < 8; ++n) acc[n] = (f32x4){0.f, 0.f, 0.f, 0.f};

  #pragma unroll
  for (int kk = 0; kk < 4; ++kk) {
    #pragma unroll
    for (int n = 0; n < 8; ++n) {
      bf16x8 wa = *(const bf16x8*)&Wl[(n * 16 + la) * WPAD + kk * 32 + kb * 8];
      acc[n] = __builtin_amdgcn_mfma_f32_16x16x32_bf16(wa, zfr[kk], acc[n], 0, 0, 0);
    }
  }

  if (node < NN) {
    #pragma unroll
    for (int n = 0; n < 8; ++n) {
      int o0 = n * 16 + kb * 4;
      ushort4 v;
      v.x = f2bf(acc[n][0]); v.y = f2bf(acc[n][1]);
      v.z = f2bf(acc[n][2]); v.w = f2bf(acc[n][3]);
      *(ushort4*)&Out[(size_t)node * Cc + o0] = v;
    }
  }
}

// BN2 stats + z materialization; bf16 P/Q gathers, XCD-bijective swizzle.
__global__ __launch_bounds__(512) void k_stats2(const unsigned short* __restrict__ P,
                                                const unsigned short* __restrict__ Q,
                                                const float* __restrict__ b1p,
                                                const int* __restrict__ tgt,
                                                const int* __restrict__ src,
                                                float* __restrict__ stats,
                                                unsigned short* __restrict__ zout) {
  __shared__ float s2[7][Cc], q2[7][Cc];
  const int nwg = NE / 512;
  const int q8 = nwg >> 3, r8 = nwg & 7;
  int orig = blockIdx.x;
  int xcd = orig & 7, idx = orig >> 3;
  int bid = (xcd < r8 ? xcd * (q8 + 1) : r8 * (q8 + 1) + (xcd - r8) * q8) + idx;
  int cp = threadIdx.x & 63;
  int y = threadIdx.x >> 6;
  int c0 = cp * 2;
  int e0 = bid * 512;
  float2 b = *(const float2*)&b1p[c0];
  float s0 = 0.f, s1 = 0.f, q0 = 0.f, q1 = 0.f;
  for (int e = e0 + y * 8; e < e0 + 512; e += 64) {
    int t[8], sr[8];
    #pragma unroll
    for (int j = 0; j < 8; ++j) { t[j] = tgt[e + j]; sr[j] = src[e + j]; }
    ushort2 pv[8], qv[8];
    #pragma unroll
    for (int j = 0; j < 8; ++j) pv[j] = *(const ushort2*)&P[(size_t)t[j] * Cc + c0];
    #pragma unroll
    for (int j = 0; j < 8; ++j) qv[j] = *(const ushort2*)&Q[(size_t)sr[j] * Cc + c0];
    #pragma unroll
    for (int j = 0; j < 8; ++j) {
      float z0 = fmaxf(bf2f(pv[j].x) + bf2f(qv[j].x) + b.x, 0.f);
      float z1 = fmaxf(bf2f(pv[j].y) + bf2f(qv[j].y) + b.y, 0.f);
      ushort2 zz; zz.x = f2bf(z0); zz.y = f2bf(z1);
      *(ushort2*)&zout[(size_t)(e + j) * 256 + c0] = zz;
      s0 += z0; s1 += z1; q0 += z0 * z0; q1 += z1 * z1;
    }
  }
  if (y) { s2[y - 1][c0] = s0; s2[y - 1][c0 + 1] = s1;
           q2[y - 1][c0] = q0; q2[y - 1][c0 + 1] = q1; }
  __syncthreads();
  if (!y) {
    #pragma unroll
    for (int j = 0; j < 7; ++j) {
      s0 += s2[j][c0]; s1 += s2[j][c0 + 1];
      q0 += q2[j][c0]; q1 += q2[j][c0 + 1];
    }
    atomicAdd(&stats[512 + c0], s0);
    atomicAdd(&stats[512 + c0 + 1], s1);
    atomicAdd(&stats[640 + c0], q0);
    atomicAdd(&stats[640 + c0 + 1], q1);
  }
}

// fold BN2 into W2, emit bf16 [o][c] weights + fp32 bias
__global__ void k_fold2(const float* __restrict__ W2, const float* __restrict__ b2,
                        const float* __restrict__ g2, const float* __restrict__ be2,
                        const float* __restrict__ stats,
                        unsigned short* __restrict__ W2bf, float* __restrict__ b2p) {
  __shared__ float red[Cc];
  int o = blockIdx.x, c = threadIdx.x;
  const float inv = 1.0f / (float)NE;
  float mu = stats[512 + c] * inv;
  float var = stats[640 + c] * inv - mu * mu;
  float a = g2[c] * rsqrtf(var + BN_EPS);
  float cc = be2[c] - mu * a;
  float w = W2[o * Cc + c];
  W2bf[o * Cc + c] = f2bf(w * a);
  red[c] = w * cc;
  __syncthreads();
  for (int s = 64; s > 0; s >>= 1) { if (c < s) red[c] += red[c + s]; __syncthreads(); }
  if (c == 0) b2p[o] = b2[o] + red[0];
}

// out[e][o] = relu( z[e]@W2' + b2' ): streaming bf16 MFMA GEMM, operand-swapped.
__global__ __launch_bounds__(256) void k_out_mfma(const unsigned short* __restrict__ zin,
                                                  const unsigned short* __restrict__ W2bf,
                                                  const float* __restrict__ b2p,
                                                  float* __restrict__ out) {
  __shared__ unsigned short Wl[128 * WPAD];
  int tid = threadIdx.x;
  int e0 = blockIdx.x * 64;

  for (int i = tid; i < 2048; i += 256) {
    int row = i >> 4, col = (i & 15) * 8;
    *(bf16x8*)&Wl[row * WPAD + col] = *(const bf16x8*)&W2bf[row * Cc + col];
  }

  int w = tid >> 6, l = tid & 63;
  int la = l & 15, kb = l >> 4;
  int e = e0 + w * 16 + la;

  bf16x8 zfr[4];
  #pragma unroll
  for (int kk = 0; kk < 4; ++kk)
    zfr[kk] = *(const bf16x8*)&zin[(size_t)e * 256 + kk * 32 + kb * 8];
  __syncthreads();

  f32x4 acc[8];
  #pragma unroll
  for (int n = 0; n < 8; ++n) acc[n] = (f32x4){0.f, 0.f, 0.f, 0.f};

  #pragma unroll
  for (int kk = 0; kk < 4; ++kk) {
    #pragma unroll
    for (int n = 0; n < 8; ++n) {
      bf16x8 wa = *(const bf16x8*)&Wl[(n * 16 + la) * WPAD + kk * 32 + kb * 8];
      acc[n] = __builtin_amdgcn_mfma_f32_16x16x32_bf16(wa, zfr[kk], acc[n], 0, 0, 0);
    }
  }

  #pragma unroll
  for (int n = 0; n < 8; ++n) {
    int o0 = n * 16 + kb * 4;
    float4 bb = *(const float4*)&b2p[o0];
    float4 v;
    v.x = fmaxf(acc[n][0] + bb.x, 0.f);
    v.y = fmaxf(acc[n][1] + bb.y, 0.f);
    v.z = fmaxf(acc[n][2] + bb.z, 0.f);
    v.w = fmaxf(acc[n][3] + bb.w, 0.f);
    *(float4*)&out[(size_t)e * Cc + o0] = v;
  }
}

extern "C" void kernel_launch(void* const* d_in, const int* in_sizes, int n_in,
                              void* d_out, int out_size, void* d_ws, size_t ws_size,
                              hipStream_t stream) {
  (void)in_sizes; (void)n_in; (void)out_size; (void)ws_size;
  const float* x   = (const float*)d_in[0];
  const float* g1  = (const float*)d_in[1];
  const float* be1 = (const float*)d_in[2];
  const float* W1  = (const float*)d_in[3];
  const float* b1  = (const float*)d_in[4];
  const float* g2  = (const float*)d_in[5];
  const float* be2 = (const float*)d_in[6];
  const float* W2  = (const float*)d_in[7];
  const float* b2  = (const float*)d_in[8];
  const int* tgt   = (const int*)d_in[9];
  const int* src   = (const int*)d_in[10];

  float* ws  = (float*)d_ws;
  float* out = (float*)d_out;

  unsigned short* P    = (unsigned short*)(ws + WS_P);
  unsigned short* xbf  = (unsigned short*)(ws + WS_XBF);
  unsigned short* Q    = (unsigned short*)(ws + WS_Q);
  float* cntT  = ws + WS_CNTT;
  int*   cntS  = (int*)(ws + WS_CNTS);
  float* stats = ws + WS_STATS;
  unsigned short* W1bf = (unsigned short*)(ws + WS_W1BF);
  float* b1p   = ws + WS_B1P;
  unsigned short* W2bf = (unsigned short*)(ws + WS_W2BF);
  float* b2p   = ws + WS_B2P;
  unsigned short* nbr  = (unsigned short*)out;  // bf16 scratch; consumed before z overwrites

  k_zero  <<<dim3((NN + 255) / 256), dim3(256), 0, stream>>>(stats, cntS);
  k_cast  <<<dim3(NN * Cc / 2048),   dim3(256), 0, stream>>>(x, xbf);
  k_nbr   <<<dim3(NN),              dim3(Cc),  0, stream>>>(xbf, tgt, src, nbr, cntT, cntS);
  k_stats1<<<dim3(512),             dim3(512), 0, stream>>>(nbr, xbf, cntT, cntS, stats);
  k_fold1 <<<dim3(Cc),              dim3(C2),  0, stream>>>(W1, b1, g1, be1, stats, W1bf, b1p);
  k_pq    <<<dim3((NN + 63) / 64, 2), dim3(256), 0, stream>>>(nbr, xbf, W1bf, P, Q);
  k_stats2<<<dim3(NE / 512),        dim3(512), 0, stream>>>(P, Q, b1p, tgt, src, stats,
                                                            (unsigned short*)out);
  k_fold2 <<<dim3(Cc),              dim3(Cc),  0, stream>>>(W2, b2, g2, be2, stats, W2bf, b2p);
  k_out_mfma<<<dim3(NE / 64),       dim3(256), 0, stream>>>((const unsigned short*)out,
                                                            W2bf, b2p, out);
}

// Round 22
// 271.909 us; speedup vs baseline: 1.2015x; 1.0336x over previous
//
#include <hip/hip_runtime.h>

#define NN 20000
#define NE 640000
#define Cc 128
#define C2 256
#define BN_EPS 1e-5f

typedef __attribute__((ext_vector_type(8))) short bf16x8;
typedef __attribute__((ext_vector_type(4))) float f32x4;

// ---- workspace layout (float offsets) ----
#define WS_P     0                      // ushort[NN*Cc] bf16 P (first half of slot)
#define WS_XBF   (NN*Cc/2)              // ushort[NN*Cc] bf16 x (second half of P slot)
#define WS_Q     (NN*Cc)                // ushort[NN*Cc] bf16 Q
#define WS_CNTT  (2*NN*Cc)              // [NN] float
#define WS_CNTS  (2*NN*Cc + NN)         // [NN] int
#define WS_STATS (2*NN*Cc + 2*NN)       // [768]
#define WS_W1BF  (WS_STATS + 768)       // ushort[2*128*128] folded W1 bf16 [half][o][c]
#define WS_B1P   (WS_W1BF + C2*Cc)      // [128]
#define WS_W2BF  (WS_B1P + Cc)          // ushort[128*128] folded W2 bf16 [o][c]
#define WS_B2P   (WS_W2BF + Cc*Cc)      // [128]

// z (bf16) for edge e lives in the FIRST 256 B of out-row e's 512 B slot.
// nbr (bf16) lives at the start of d_out until k_pq consumes it.

static __device__ inline unsigned short f2bf(float f) {
  union { float f; unsigned u; } v; v.f = f;
  unsigned r = v.u + 0x7fffu + ((v.u >> 16) & 1u);
  return (unsigned short)(r >> 16);
}
static __device__ inline float bf2f(unsigned short h) {
  union { unsigned u; float f; } v; v.u = (unsigned)h << 16; return v.f;
}

// merged: zero stats/cntS + cast x->bf16. grid = NN*Cc/2048 = 1250 blocks.
__global__ __launch_bounds__(256) void k_prep(const float* __restrict__ x,
                                              unsigned short* __restrict__ xbf,
                                              float* __restrict__ stats,
                                              int* __restrict__ cntS) {
  int g = blockIdx.x * 256 + threadIdx.x;
  if (g < 768) stats[g] = 0.0f;
  if (g < NN) cntS[g] = 0;
  int i = g * 8;
  float4 v0 = *(const float4*)&x[i];
  float4 v1 = *(const float4*)&x[i + 4];
  bf16x8 o;
  o[0] = (short)f2bf(v0.x); o[1] = (short)f2bf(v0.y);
  o[2] = (short)f2bf(v0.z); o[3] = (short)f2bf(v0.w);
  o[4] = (short)f2bf(v1.x); o[5] = (short)f2bf(v1.y);
  o[6] = (short)f2bf(v1.z); o[7] = (short)f2bf(v1.w);
  *(bf16x8*)&xbf[i] = o;
}

// one block (128 threads) per node: segment sum of bf16 x + fused src-histogram.
__global__ void k_nbr(const unsigned short* __restrict__ xbf, const int* __restrict__ tgt,
                      const int* __restrict__ src, unsigned short* __restrict__ nbr,
                      float* __restrict__ cntT, int* __restrict__ cntS) {
  int node = blockIdx.x;
  int a = 0, b = NE;
  while (a < b) { int m = (a + b) >> 1; if (tgt[m] < node) a = m + 1; else b = m; }
  int lo = a;
  b = NE;
  while (a < b) { int m = (a + b) >> 1; if (tgt[m] <= node) a = m + 1; else b = m; }
  int hi = a;
  int c = threadIdx.x;
  for (int e = lo + c; e < hi; e += 128) atomicAdd(&cntS[src[e]], 1);
  float a0 = 0.f, a1 = 0.f, a2 = 0.f, a3 = 0.f;
  int e = lo;
  for (; e + 7 < hi; e += 8) {
    int s0 = src[e],     s1 = src[e + 1], s2 = src[e + 2], s3 = src[e + 3];
    int s4 = src[e + 4], s5 = src[e + 5], s6 = src[e + 6], s7 = src[e + 7];
    float v0 = bf2f(xbf[(size_t)s0 * Cc + c]), v1 = bf2f(xbf[(size_t)s1 * Cc + c]);
    float v2 = bf2f(xbf[(size_t)s2 * Cc + c]), v3 = bf2f(xbf[(size_t)s3 * Cc + c]);
    float v4 = bf2f(xbf[(size_t)s4 * Cc + c]), v5 = bf2f(xbf[(size_t)s5 * Cc + c]);
    float v6 = bf2f(xbf[(size_t)s6 * Cc + c]), v7 = bf2f(xbf[(size_t)s7 * Cc + c]);
    a0 += v0 + v4; a1 += v1 + v5; a2 += v2 + v6; a3 += v3 + v7;
  }
  for (; e < hi; ++e) a0 += bf2f(xbf[(size_t)src[e] * Cc + c]);
  nbr[(size_t)node * Cc + c] = f2bf((a0 + a1) + (a2 + a3));
  if (c == 0) cntT[node] = (float)(hi - lo);
}

// BN1 stats from bf16 tables. 512 blocks x 512 threads.
__global__ __launch_bounds__(512) void k_stats1(const unsigned short* __restrict__ nbr,
                                                const unsigned short* __restrict__ xbf,
                                                const float* __restrict__ cntT,
                                                const int* __restrict__ cntS,
                                                float* __restrict__ stats) {
  __shared__ float ls[3][4][Cc];
  int c = threadIdx.x & 127;
  int y = threadIdx.x >> 7;
  float sa = 0.f, qa = 0.f, sb = 0.f, qb = 0.f;
  for (int t = blockIdx.x + y * 512; t < NN; t += 2048) {
    float ct = cntT[t];
    float cs = (float)cntS[t];
    float v1 = bf2f(nbr[(size_t)t * Cc + c]);
    float v2 = bf2f(xbf[(size_t)t * Cc + c]);
    sa += ct * v1; qa += ct * v1 * v1;
    sb += cs * v2; qb += cs * v2 * v2;
  }
  if (y) {
    ls[y - 1][0][c] = sa; ls[y - 1][1][c] = qa;
    ls[y - 1][2][c] = sb; ls[y - 1][3][c] = qb;
  }
  __syncthreads();
  if (!y) {
    #pragma unroll
    for (int j = 0; j < 3; ++j) {
      sa += ls[j][0][c]; qa += ls[j][1][c];
      sb += ls[j][2][c]; qb += ls[j][3][c];
    }
    atomicAdd(&stats[c], sa);
    atomicAdd(&stats[256 + c], qa);
    atomicAdd(&stats[128 + c], sb);
    atomicAdd(&stats[256 + 128 + c], qb);
  }
}

// fold BN1 into W1 -> bf16 [half][o][c] + fp32 b1p
__global__ void k_fold1(const float* __restrict__ W1, const float* __restrict__ b1,
                        const float* __restrict__ g1, const float* __restrict__ be1,
                        const float* __restrict__ stats,
                        unsigned short* __restrict__ W1bf, float* __restrict__ b1p) {
  __shared__ float red[C2];
  int o = blockIdx.x, c = threadIdx.x;
  const float inv = 1.0f / (float)NE;
  float mu = stats[c] * inv;
  float var = stats[256 + c] * inv - mu * mu;
  float a = g1[c] * rsqrtf(var + BN_EPS);
  float cc = be1[c] - mu * a;
  float w = W1[o * C2 + c];
  W1bf[(size_t)(c >> 7) * Cc * Cc + o * Cc + (c & 127)] = f2bf(w * a);
  red[c] = w * cc;
  __syncthreads();
  for (int s = 128; s > 0; s >>= 1) { if (c < s) red[c] += red[c + s]; __syncthreads(); }
  if (c == 0) b1p[o] = b1[o] + red[0];
}

// P = nbr@W1a'.T ; Q = x@W1b'.T  via bf16 MFMA (swapped ops), tail-guarded.
#define WPAD 136
__global__ __launch_bounds__(256) void k_pq(const unsigned short* __restrict__ nbr,
                                            const unsigned short* __restrict__ xbf,
                                            const unsigned short* __restrict__ W1bf,
                                            unsigned short* __restrict__ P,
                                            unsigned short* __restrict__ Q) {
  __shared__ unsigned short Wl[128 * WPAD];
  const int half = blockIdx.y;
  const unsigned short* __restrict__ A = half ? xbf : nbr;
  unsigned short* __restrict__ Out = half ? Q : P;
  const unsigned short* __restrict__ Wt = W1bf + (size_t)half * Cc * Cc;
  int tid = threadIdx.x;
  int n0 = blockIdx.x * 64;

  for (int i = tid; i < 2048; i += 256) {
    int row = i >> 4, col = (i & 15) * 8;
    *(bf16x8*)&Wl[row * WPAD + col] = *(const bf16x8*)&Wt[row * Cc + col];
  }

  int w = tid >> 6, l = tid & 63;
  int la = l & 15, kb = l >> 4;
  int node = n0 + w * 16 + la;
  int ld = node < NN ? node : NN - 1;

  bf16x8 zfr[4];
  #pragma unroll
  for (int kk = 0; kk < 4; ++kk)
    zfr[kk] = *(const bf16x8*)&A[(size_t)ld * Cc + kk * 32 + kb * 8];
  __syncthreads();

  f32x4 acc[8];
  #pragma unroll
  for (int n = 0; n < 8; ++n) acc[n] = (f32x4){0.f, 0.f, 0.f, 0.f};

  #pragma unroll
  for (int kk = 0; kk < 4; ++kk) {
    #pragma unroll
    for (int n = 0; n < 8; ++n) {
      bf16x8 wa = *(const bf16x8*)&Wl[(n * 16 + la) * WPAD + kk * 32 + kb * 8];
      acc[n] = __builtin_amdgcn_mfma_f32_16x16x32_bf16(wa, zfr[kk], acc[n], 0, 0, 0);
    }
  }

  if (node < NN) {
    #pragma unroll
    for (int n = 0; n < 8; ++n) {
      int o0 = n * 16 + kb * 4;
      ushort4 v;
      v.x = f2bf(acc[n][0]); v.y = f2bf(acc[n][1]);
      v.z = f2bf(acc[n][2]); v.w = f2bf(acc[n][3]);
      *(ushort4*)&Out[(size_t)node * Cc + o0] = v;
    }
  }
}

// BN2 stats + z materialization; bf16 P/Q gathers, XCD-bijective swizzle.
__global__ __launch_bounds__(512) void k_stats2(const unsigned short* __restrict__ P,
                                                const unsigned short* __restrict__ Q,
                                                const float* __restrict__ b1p,
                                                const int* __restrict__ tgt,
                                                const int* __restrict__ src,
                                                float* __restrict__ stats,
                                                unsigned short* __restrict__ zout) {
  __shared__ float s2[7][Cc], q2[7][Cc];
  const int nwg = NE / 512;
  const int q8 = nwg >> 3, r8 = nwg & 7;
  int orig = blockIdx.x;
  int xcd = orig & 7, idx = orig >> 3;
  int bid = (xcd < r8 ? xcd * (q8 + 1) : r8 * (q8 + 1) + (xcd - r8) * q8) + idx;
  int cp = threadIdx.x & 63;
  int y = threadIdx.x >> 6;
  int c0 = cp * 2;
  int e0 = bid * 512;
  float2 b = *(const float2*)&b1p[c0];
  float s0 = 0.f, s1 = 0.f, q0 = 0.f, q1 = 0.f;
  for (int e = e0 + y * 8; e < e0 + 512; e += 64) {
    int t[8], sr[8];
    #pragma unroll
    for (int j = 0; j < 8; ++j) { t[j] = tgt[e + j]; sr[j] = src[e + j]; }
    ushort2 pv[8], qv[8];
    #pragma unroll
    for (int j = 0; j < 8; ++j) pv[j] = *(const ushort2*)&P[(size_t)t[j] * Cc + c0];
    #pragma unroll
    for (int j = 0; j < 8; ++j) qv[j] = *(const ushort2*)&Q[(size_t)sr[j] * Cc + c0];
    #pragma unroll
    for (int j = 0; j < 8; ++j) {
      float z0 = fmaxf(bf2f(pv[j].x) + bf2f(qv[j].x) + b.x, 0.f);
      float z1 = fmaxf(bf2f(pv[j].y) + bf2f(qv[j].y) + b.y, 0.f);
      ushort2 zz; zz.x = f2bf(z0); zz.y = f2bf(z1);
      *(ushort2*)&zout[(size_t)(e + j) * 256 + c0] = zz;
      s0 += z0; s1 += z1; q0 += z0 * z0; q1 += z1 * z1;
    }
  }
  if (y) { s2[y - 1][c0] = s0; s2[y - 1][c0 + 1] = s1;
           q2[y - 1][c0] = q0; q2[y - 1][c0 + 1] = q1; }
  __syncthreads();
  if (!y) {
    #pragma unroll
    for (int j = 0; j < 7; ++j) {
      s0 += s2[j][c0]; s1 += s2[j][c0 + 1];
      q0 += q2[j][c0]; q1 += q2[j][c0 + 1];
    }
    atomicAdd(&stats[512 + c0], s0);
    atomicAdd(&stats[512 + c0 + 1], s1);
    atomicAdd(&stats[640 + c0], q0);
    atomicAdd(&stats[640 + c0 + 1], q1);
  }
}

// fold BN2 into W2, emit bf16 [o][c] weights + fp32 bias
__global__ void k_fold2(const float* __restrict__ W2, const float* __restrict__ b2,
                        const float* __restrict__ g2, const float* __restrict__ be2,
                        const float* __restrict__ stats,
                        unsigned short* __restrict__ W2bf, float* __restrict__ b2p) {
  __shared__ float red[Cc];
  int o = blockIdx.x, c = threadIdx.x;
  const float inv = 1.0f / (float)NE;
  float mu = stats[512 + c] * inv;
  float var = stats[640 + c] * inv - mu * mu;
  float a = g2[c] * rsqrtf(var + BN_EPS);
  float cc = be2[c] - mu * a;
  float w = W2[o * Cc + c];
  W2bf[o * Cc + c] = f2bf(w * a);
  red[c] = w * cc;
  __syncthreads();
  for (int s = 64; s > 0; s >>= 1) { if (c < s) red[c] += red[c + s]; __syncthreads(); }
  if (c == 0) b2p[o] = b2[o] + red[0];
}

// out[e][o] = relu( z[e]@W2' + b2' ): streaming bf16 MFMA GEMM, operand-swapped.
// Final stores NON-TEMPORAL via ext-vector f32x4 (the builtin rejects HIP's
// struct float4): out is never re-read; keeps the 164 MB z table L3-resident.
__global__ __launch_bounds__(256) void k_out_mfma(const unsigned short* __restrict__ zin,
                                                  const unsigned short* __restrict__ W2bf,
                                                  const float* __restrict__ b2p,
                                                  float* __restrict__ out) {
  __shared__ unsigned short Wl[128 * WPAD];
  int tid = threadIdx.x;
  int e0 = blockIdx.x * 64;

  for (int i = tid; i < 2048; i += 256) {
    int row = i >> 4, col = (i & 15) * 8;
    *(bf16x8*)&Wl[row * WPAD + col] = *(const bf16x8*)&W2bf[row * Cc + col];
  }

  int w = tid >> 6, l = tid & 63;
  int la = l & 15, kb = l >> 4;
  int e = e0 + w * 16 + la;

  bf16x8 zfr[4];
  #pragma unroll
  for (int kk = 0; kk < 4; ++kk)
    zfr[kk] = *(const bf16x8*)&zin[(size_t)e * 256 + kk * 32 + kb * 8];
  __syncthreads();

  f32x4 acc[8];
  #pragma unroll
  for (int n = 0; n < 8; ++n) acc[n] = (f32x4){0.f, 0.f, 0.f, 0.f};

  #pragma unroll
  for (int kk = 0; kk < 4; ++kk) {
    #pragma unroll
    for (int n = 0; n < 8; ++n) {
      bf16x8 wa = *(const bf16x8*)&Wl[(n * 16 + la) * WPAD + kk * 32 + kb * 8];
      acc[n] = __builtin_amdgcn_mfma_f32_16x16x32_bf16(wa, zfr[kk], acc[n], 0, 0, 0);
    }
  }

  #pragma unroll
  for (int n = 0; n < 8; ++n) {
    int o0 = n * 16 + kb * 4;
    float4 bb = *(const float4*)&b2p[o0];
    f32x4 v;
    v[0] = fmaxf(acc[n][0] + bb.x, 0.f);
    v[1] = fmaxf(acc[n][1] + bb.y, 0.f);
    v[2] = fmaxf(acc[n][2] + bb.z, 0.f);
    v[3] = fmaxf(acc[n][3] + bb.w, 0.f);
    __builtin_nontemporal_store(v, (f32x4*)&out[(size_t)e * Cc + o0]);
  }
}

extern "C" void kernel_launch(void* const* d_in, const int* in_sizes, int n_in,
                              void* d_out, int out_size, void* d_ws, size_t ws_size,
                              hipStream_t stream) {
  (void)in_sizes; (void)n_in; (void)out_size; (void)ws_size;
  const float* x   = (const float*)d_in[0];
  const float* g1  = (const float*)d_in[1];
  const float* be1 = (const float*)d_in[2];
  const float* W1  = (const float*)d_in[3];
  const float* b1  = (const float*)d_in[4];
  const float* g2  = (const float*)d_in[5];
  const float* be2 = (const float*)d_in[6];
  const float* W2  = (const float*)d_in[7];
  const float* b2  = (const float*)d_in[8];
  const int* tgt   = (const int*)d_in[9];
  const int* src   = (const int*)d_in[10];

  float* ws  = (float*)d_ws;
  float* out = (float*)d_out;

  unsigned short* P    = (unsigned short*)(ws + WS_P);
  unsigned short* xbf  = (unsigned short*)(ws + WS_XBF);
  unsigned short* Q    = (unsigned short*)(ws + WS_Q);
  float* cntT  = ws + WS_CNTT;
  int*   cntS  = (int*)(ws + WS_CNTS);
  float* stats = ws + WS_STATS;
  unsigned short* W1bf = (unsigned short*)(ws + WS_W1BF);
  float* b1p   = ws + WS_B1P;
  unsigned short* W2bf = (unsigned short*)(ws + WS_W2BF);
  float* b2p   = ws + WS_B2P;
  unsigned short* nbr  = (unsigned short*)out;  // bf16 scratch; consumed before z overwrites

  k_prep  <<<dim3(NN * Cc / 2048),   dim3(256), 0, stream>>>(x, xbf, stats, cntS);
  k_nbr   <<<dim3(NN),              dim3(Cc),  0, stream>>>(xbf, tgt, src, nbr, cntT, cntS);
  k_stats1<<<dim3(512),             dim3(512), 0, stream>>>(nbr, xbf, cntT, cntS, stats);
  k_fold1 <<<dim3(Cc),              dim3(C2),  0, stream>>>(W1, b1, g1, be1, stats, W1bf, b1p);
  k_pq    <<<dim3((NN + 63) / 64, 2), dim3(256), 0, stream>>>(nbr, xbf, W1bf, P, Q);
  k_stats2<<<dim3(NE / 512),        dim3(512), 0, stream>>>(P, Q, b1p, tgt, src, stats,
                                                            (unsigned short*)out);
  k_fold2 <<<dim3(Cc),              dim3(Cc),  0, stream>>>(W2, b2, g2, be2, stats, W2bf, b2p);
  k_out_mfma<<<dim3(NE / 64),       dim3(256), 0, stream>>>((const unsigned short*)out,
                                                            W2bf, b2p, out);
}